// Round 5
// baseline (969.575 us; speedup 1.0000x reference)
//
#include <hip/hip_runtime.h>

// Fused 4-layer MLP (2 -> 1024 -> 512 -> 256 -> 3), N = 262144, fp32 I/O.
// R5: 1024 threads (16 waves), 64 rows/block, 4096 blocks.
// acc2 = 32 regs/thread (the R2-R4 spill was acc2=64 + working set > 128-reg
// budget; 16-wave blocks pin the budget at 4 waves/SIMD = 128, so shrink acc).
// Wave owns 2 j-tiles x 1 m-tile: one LDS bf read feeds two MFMAs.
// fp16 MFMA 32x32x16, fp32 accumulate, transposed layers D[feat][batch].

typedef _Float16 f16;
typedef f16 f16x8 __attribute__((ext_vector_type(8)));
typedef f16 f16x4 __attribute__((ext_vector_type(4)));
typedef float f32x16 __attribute__((ext_vector_type(16)));

#define MFMA(a, b, c) __builtin_amdgcn_mfma_f32_32x32x16_f16((a), (b), (c), 0, 0, 0)

// ws layout in 16-byte units (f16x8):
//  W1F : [16 jt][64 ks][64 lane]            ->      0 .. 65536
//  W2F : [ 8 jt][32 ks][64 lane]            ->  65536 .. 81920
//  W3F : [16 ks][64 lane]                   ->  81920 .. 82944
//  P0F : [32 k1t][64 lane] (layer1 A frag)  ->  82944 .. 84992
//  B1F : [16 jt][64 lane]                   ->  84992 .. 86016
//  B2F : [ 8 jt][64 lane]                   ->  86016 .. 86528
#define U_W1F 0
#define U_W2F 65536
#define U_W3F 81920
#define U_P0F 82944
#define U_B1F 84992
#define U_B2F 86016
#define U_TOTAL 86528

__global__ void prep_kernel(const float* __restrict__ W0, const float* __restrict__ b0,
                            const float* __restrict__ W1, const float* __restrict__ b1,
                            const float* __restrict__ W2, const float* __restrict__ b2,
                            const float* __restrict__ W3, f16* __restrict__ ws)
{
    int u = blockIdx.x * 256 + threadIdx.x;
    if (u >= U_TOTAL) return;
    int lane = u & 63;
    int l31 = lane & 31;
    int q = lane >> 5;
    f16x8 v;
#pragma unroll
    for (int e = 0; e < 8; ++e) v[e] = (f16)0.f;

    if (u < U_W2F) {                       // W1F: W1 is [1024][512]
        int jt = u >> 12, ks = (u >> 6) & 63;
        int j = jt * 32 + l31;
        int kb = ks * 16 + q * 8;
        const float* p = W1 + (size_t)kb * 512 + j;
#pragma unroll
        for (int e = 0; e < 8; ++e) v[e] = (f16)p[(size_t)e * 512];
    } else if (u < U_W3F) {                // W2F: W2 is [512][256]
        int t = u - U_W2F;
        int jt = t >> 11, ks = (t >> 6) & 31;
        int j = jt * 32 + l31;
        int kb = ks * 16 + q * 8;
        const float* p = W2 + (size_t)kb * 256 + j;
#pragma unroll
        for (int e = 0; e < 8; ++e) v[e] = (f16)p[(size_t)e * 256];
    } else if (u < U_P0F) {                // W3F: W3 is [256][3], pad j>=3 with 0
        int t = u - U_W3F;
        int ks = t >> 6;
        int j = l31;
        int kb = ks * 16 + q * 8;
        if (j < 3) {
            const float* p = W3 + (size_t)kb * 3 + j;
#pragma unroll
            for (int e = 0; e < 8; ++e) v[e] = (f16)p[(size_t)e * 3];
        }
    } else if (u < U_B1F) {                // P0F: layer-1 A frag with hi/lo split + bias
        int t = u - U_P0F;
        int jt = t >> 6;
        int j = jt * 32 + l31;
        if (q == 0) {
            float w00 = W0[j], w01 = W0[1024 + j], bb = b0[j];
            f16 w00h = (f16)w00, w01h = (f16)w01, bh = (f16)bb;
            v[0] = w00h; v[1] = w01h; v[2] = bh;
            v[3] = w00h; v[4] = w01h;                       // pair with x_lo
            v[5] = (f16)(w00 - (float)w00h);                // w_lo * x_hi
            v[6] = (f16)(w01 - (float)w01h);
            v[7] = (f16)(bb - (float)bh);                   // bias residual * 1
        }
    } else if (u < U_B2F) {                // B1F
        int t = u - U_B1F;
        int jt = t >> 6;
        int j = jt * 32 + l31;
        if (q == 0) v[0] = (f16)b1[j];
    } else {                               // B2F
        int t = u - U_B2F;
        int jt = t >> 6;
        int j = jt * 32 + l31;
        if (q == 0) v[0] = (f16)b2[j];
    }
    ((f16x8*)ws)[u] = v;
}

// ---- LDS slab helpers. Slab rows: [m][k] f16, row stride rs bytes.
// XOR swizzle at 8-byte granularity: phys_dw = dw ^ ((m&15)<<1).
// 2-way-max bank conflicts (free) for both b64 writes and reads.
__device__ __forceinline__ void slab_write4(unsigned char* lds, int m, int dw /*even*/,
                                            int rs, f16x4 val)
{
    int s = (m & 15) << 1;
    *(f16x4*)(lds + (size_t)m * rs + (size_t)((dw ^ s) << 2)) = val;
}

__device__ __forceinline__ f16x8 slab_read8(const unsigned char* lds, int m, int dw /*mult of 4*/,
                                            int rs)
{
    int s = (m & 15) << 1;
    f16x4 lo = *(const f16x4*)(lds + (size_t)m * rs + (size_t)((dw ^ s) << 2));
    f16x4 hi = *(const f16x4*)(lds + (size_t)m * rs + (size_t)(((dw + 2) ^ s) << 2));
    union { f16x8 v; f16x4 p[2]; } u;
    u.p[0] = lo; u.p[1] = hi;
    return u.v;
}

__device__ __forceinline__ f16x4 relu_pack4(const f32x16& d, int t)
{
    f16x4 pk;
#pragma unroll
    for (int r = 0; r < 4; ++r) {
        float v = d[4 * t + r];
        pk[r] = (f16)(v > 0.f ? v : 0.f);
    }
    return pk;
}

__global__ __launch_bounds__(1024)
void mlp_kernel(const float* __restrict__ X, const float* __restrict__ b3,
                const f16* __restrict__ ws, float* __restrict__ out)
{
    const f16x8* W1F = (const f16x8*)ws + U_W1F;
    const f16x8* W2F = (const f16x8*)ws + U_W2F;
    const f16x8* W3F = (const f16x8*)ws + U_W3F;
    const f16x8* P0F = (const f16x8*)ws + U_P0F;
    const f16x8* B1F = (const f16x8*)ws + U_B1F;
    const f16x8* B2F = (const f16x8*)ws + U_B2F;

    __shared__ __align__(16) unsigned char lds[65536];

    const int tid  = threadIdx.x;
    const int w    = tid >> 6;       // wave 0..15
    const int lane = tid & 63;
    const int l31  = lane & 31;
    const int q    = lane >> 5;
    const size_t rowbase = (size_t)blockIdx.x * 64;

    f32x16 zero16;
#pragma unroll
    for (int i = 0; i < 16; ++i) zero16[i] = 0.f;

    // ones frag for bias-init MFMAs
    f16x8 ones;
#pragma unroll
    for (int e = 0; e < 8; ++e) ones[e] = (f16)0.f;
    if (q == 0) ones[0] = (f16)1.f;

    // Layer-1 split: per chunk 8 k1-tiles x 2 m-tiles = 16 units = 16 waves.
    // Wave w: k1loc = w>>1, m-tile mtL1 = w&1.
    const int mtL1 = w & 1;
    f16x8 xfrag;
    {
        f16x8 v;
#pragma unroll
        for (int e = 0; e < 8; ++e) v[e] = (f16)0.f;
        if (q == 0) {
            float2 xv = ((const float2*)X)[rowbase + mtL1 * 32 + l31];
            f16 x0h = (f16)xv.x, x1h = (f16)xv.y;
            v[0] = x0h; v[1] = x1h; v[2] = (f16)1.f;
            v[3] = (f16)(xv.x - (float)x0h);
            v[4] = (f16)(xv.y - (float)x1h);
            v[5] = x0h; v[6] = x1h; v[7] = (f16)1.f;
        }
        xfrag = v;
    }

    // Layer-2 ownership: wave w -> j-tiles jt0 = 2*(w&7), jt0+1; m-tile mt2 = w>>3.
    const int jt0 = (w & 7) * 2;
    const int mt2 = w >> 3;
    f32x16 acc2[2];
    acc2[0] = MFMA(B1F[jt0 * 64 + lane], ones, zero16);
    acc2[1] = MFMA(B1F[(jt0 + 1) * 64 + lane], ones, zero16);

    // ---- fused layer1 + layer2: K chunked 4 x 256 through slab (64 rows, rs=512B)
    for (int c = 0; c < 4; ++c) {
        // layer 1: one (k1,mt) unit per wave
        {
            int k1loc = w >> 1;
            f16x8 af1 = P0F[(c * 8 + k1loc) * 64 + lane];
            f32x16 d = MFMA(af1, xfrag, zero16);
            int m = mtL1 * 32 + l31;              // D col -> batch row
            int kb = k1loc * 32 + 4 * q;          // D row -> h1 feat (chunk-local)
#pragma unroll
            for (int t = 0; t < 4; ++t)
                slab_write4(lds, m, (kb + 8 * t) >> 1, 512, relu_pack4(d, t));
        }
        __syncthreads();
        // layer 2 partial K: 16 ks; 2 af (global/L2), 1 bf (LDS), 2 MFMA
        for (int ks = 0; ks < 16; ++ks) {
            int ksg = c * 16 + ks;
            f16x8 af0 = W1F[(jt0 * 64 + ksg) * 64 + lane];
            f16x8 af1 = W1F[((jt0 + 1) * 64 + ksg) * 64 + lane];
            f16x8 bf = slab_read8(lds, mt2 * 32 + l31, (ks * 16 + q * 8) >> 1, 512);
            acc2[0] = MFMA(af0, bf, acc2[0]);
            acc2[1] = MFMA(af1, bf, acc2[1]);
        }
        __syncthreads();
    }

    // ---- stage h2 (64 rows x 512 feats = 64KB, rs=1024B); acc2 dies here
#pragma unroll
    for (int ji = 0; ji < 2; ++ji) {
        int jb = (jt0 + ji) * 32 + 4 * q;
#pragma unroll
        for (int t = 0; t < 4; ++t)
            slab_write4(lds, mt2 * 32 + l31, (jb + 8 * t) >> 1, 1024,
                        relu_pack4(acc2[ji], t));
    }
    __syncthreads();

    // ---- layer 3 full-K (512): 8 j-tiles x 2 m-tiles = 16 units = 16 waves
    const int jt3 = w & 7;
    const int mt3 = w >> 3;
    f32x16 acc3 = MFMA(B2F[jt3 * 64 + lane], ones, zero16);
    for (int ks = 0; ks < 32; ++ks) {
        f16x8 af = W2F[(jt3 * 32 + ks) * 64 + lane];
        f16x8 bf = slab_read8(lds, mt3 * 32 + l31, (ks * 16 + q * 8) >> 1, 1024);
        acc3 = MFMA(af, bf, acc3);
    }
    __syncthreads();   // h2 reads done before overwriting slab with h3

    // ---- stage h3 (64 rows x 256 feats = 32KB, rs=512B); acc3 dies here
    {
        int jb = jt3 * 32 + 4 * q;
#pragma unroll
        for (int t = 0; t < 4; ++t)
            slab_write4(lds, mt3 * 32 + l31, (jb + 8 * t) >> 1, 512,
                        relu_pack4(acc3, t));
    }
    __syncthreads();

    // ---- layer 4: waves 0,1 -> the two 32-row tiles (j padded to 32, 3 valid)
    if (w < 2) {
        f32x16 acc4 = zero16;
        for (int ks = 0; ks < 16; ++ks) {
            f16x8 af = W3F[ks * 64 + lane];
            f16x8 bf = slab_read8(lds, w * 32 + l31, (ks * 16 + q * 8) >> 1, 512);
            acc4 = MFMA(af, bf, acc4);
        }
        if (q == 0) {
            size_t gm = rowbase + w * 32 + l31;
            out[gm * 3 + 0] = acc4[0] + b3[0];
            out[gm * 3 + 1] = acc4[1] + b3[1];
            out[gm * 3 + 2] = acc4[2] + b3[2];
        }
    }
}

extern "C" void kernel_launch(void* const* d_in, const int* in_sizes, int n_in,
                              void* d_out, int out_size, void* d_ws, size_t ws_size,
                              hipStream_t stream)
{
    const float* X  = (const float*)d_in[0];
    const float* W0 = (const float*)d_in[1];
    const float* b0 = (const float*)d_in[2];
    const float* W1 = (const float*)d_in[3];
    const float* b1 = (const float*)d_in[4];
    const float* W2 = (const float*)d_in[5];
    const float* b2 = (const float*)d_in[6];
    const float* W3 = (const float*)d_in[7];
    const float* b3 = (const float*)d_in[8];
    f16* ws = (f16*)d_ws;

    int N = in_sizes[0] / 2;          // 262144
    int nblk = N / 64;                // 4096

    prep_kernel<<<(U_TOTAL + 255) / 256, 256, 0, stream>>>(W0, b0, W1, b1, W2, b2, W3, ws);
    mlp_kernel<<<nblk, 1024, 0, stream>>>(X, b3, ws, (float*)d_out);
}

// Round 6
// 422.633 us; speedup vs baseline: 2.2941x; 2.2941x over previous
//
#include <hip/hip_runtime.h>

// Fused 4-layer MLP (2 -> 1024 -> 512 -> 256 -> 3), N = 262144, fp32 I/O.
// R6: 512 threads (8 waves), 64 rows/block, 4096 blocks.
// 8-wave blocks -> 2 waves/SIMD -> 256-reg/thread budget: spill-free by
// construction (R2-R5: 16-wave blocks pin budget at 128, arch split at 64,
// guaranteed spill). Wave owns 2 jt x 2 mt; 2 LDS reads feed 4 MFMAs.
// fp16 MFMA 32x32x16, fp32 accumulate, transposed layers D[feat][batch].

typedef _Float16 f16;
typedef f16 f16x8 __attribute__((ext_vector_type(8)));
typedef f16 f16x4 __attribute__((ext_vector_type(4)));
typedef float f32x16 __attribute__((ext_vector_type(16)));

#define MFMA(a, b, c) __builtin_amdgcn_mfma_f32_32x32x16_f16((a), (b), (c), 0, 0, 0)

// ws layout in 16-byte units (f16x8):
//  W1F : [16 jt][64 ks][64 lane]            ->      0 .. 65536
//  W2F : [ 8 jt][32 ks][64 lane]            ->  65536 .. 81920
//  W3F : [16 ks][64 lane]                   ->  81920 .. 82944
//  P0F : [32 k1t][64 lane] (layer1 A frag)  ->  82944 .. 84992
//  B1F : [16 jt][64 lane]                   ->  84992 .. 86016
//  B2F : [ 8 jt][64 lane]                   ->  86016 .. 86528
#define U_W1F 0
#define U_W2F 65536
#define U_W3F 81920
#define U_P0F 82944
#define U_B1F 84992
#define U_B2F 86016
#define U_TOTAL 86528

__global__ void prep_kernel(const float* __restrict__ W0, const float* __restrict__ b0,
                            const float* __restrict__ W1, const float* __restrict__ b1,
                            const float* __restrict__ W2, const float* __restrict__ b2,
                            const float* __restrict__ W3, f16* __restrict__ ws)
{
    int u = blockIdx.x * 256 + threadIdx.x;
    if (u >= U_TOTAL) return;
    int lane = u & 63;
    int l31 = lane & 31;
    int q = lane >> 5;
    f16x8 v;
#pragma unroll
    for (int e = 0; e < 8; ++e) v[e] = (f16)0.f;

    if (u < U_W2F) {                       // W1F: W1 is [1024][512]
        int jt = u >> 12, ks = (u >> 6) & 63;
        int j = jt * 32 + l31;
        int kb = ks * 16 + q * 8;
        const float* p = W1 + (size_t)kb * 512 + j;
#pragma unroll
        for (int e = 0; e < 8; ++e) v[e] = (f16)p[(size_t)e * 512];
    } else if (u < U_W3F) {                // W2F: W2 is [512][256]
        int t = u - U_W2F;
        int jt = t >> 11, ks = (t >> 6) & 31;
        int j = jt * 32 + l31;
        int kb = ks * 16 + q * 8;
        const float* p = W2 + (size_t)kb * 256 + j;
#pragma unroll
        for (int e = 0; e < 8; ++e) v[e] = (f16)p[(size_t)e * 256];
    } else if (u < U_P0F) {                // W3F: W3 is [256][3], pad j>=3 with 0
        int t = u - U_W3F;
        int ks = t >> 6;
        int j = l31;
        int kb = ks * 16 + q * 8;
        if (j < 3) {
            const float* p = W3 + (size_t)kb * 3 + j;
#pragma unroll
            for (int e = 0; e < 8; ++e) v[e] = (f16)p[(size_t)e * 3];
        }
    } else if (u < U_B1F) {                // P0F: layer-1 A frag with hi/lo split + bias
        int t = u - U_P0F;
        int jt = t >> 6;
        int j = jt * 32 + l31;
        if (q == 0) {
            float w00 = W0[j], w01 = W0[1024 + j], bb = b0[j];
            f16 w00h = (f16)w00, w01h = (f16)w01, bh = (f16)bb;
            v[0] = w00h; v[1] = w01h; v[2] = bh;
            v[3] = w00h; v[4] = w01h;                       // pair with x_lo
            v[5] = (f16)(w00 - (float)w00h);                // w_lo * x_hi
            v[6] = (f16)(w01 - (float)w01h);
            v[7] = (f16)(bb - (float)bh);                   // bias residual * 1
        }
    } else if (u < U_B2F) {                // B1F
        int t = u - U_B1F;
        int jt = t >> 6;
        int j = jt * 32 + l31;
        if (q == 0) v[0] = (f16)b1[j];
    } else {                               // B2F
        int t = u - U_B2F;
        int jt = t >> 6;
        int j = jt * 32 + l31;
        if (q == 0) v[0] = (f16)b2[j];
    }
    ((f16x8*)ws)[u] = v;
}

// ---- LDS slab helpers. Slab rows: [m][k] f16, row stride rs bytes.
// XOR swizzle at 8-byte granularity: phys_dw = dw ^ ((m&15)<<1).
// 2-way-max bank conflicts (free) for both b64 writes and reads.
__device__ __forceinline__ void slab_write4(unsigned char* lds, int m, int dw /*even*/,
                                            int rs, f16x4 val)
{
    int s = (m & 15) << 1;
    *(f16x4*)(lds + (size_t)m * rs + (size_t)((dw ^ s) << 2)) = val;
}

__device__ __forceinline__ f16x8 slab_read8(const unsigned char* lds, int m, int dw /*mult of 4*/,
                                            int rs)
{
    int s = (m & 15) << 1;
    f16x4 lo = *(const f16x4*)(lds + (size_t)m * rs + (size_t)((dw ^ s) << 2));
    f16x4 hi = *(const f16x4*)(lds + (size_t)m * rs + (size_t)(((dw + 2) ^ s) << 2));
    union { f16x8 v; f16x4 p[2]; } u;
    u.p[0] = lo; u.p[1] = hi;
    return u.v;
}

__device__ __forceinline__ f16x4 relu_pack4(const f32x16& d, int t)
{
    f16x4 pk;
#pragma unroll
    for (int r = 0; r < 4; ++r) {
        float v = d[4 * t + r];
        pk[r] = (f16)(v > 0.f ? v : 0.f);
    }
    return pk;
}

__global__ __launch_bounds__(512)
void mlp_kernel(const float* __restrict__ X, const float* __restrict__ b3,
                const f16* __restrict__ ws, float* __restrict__ out)
{
    const f16x8* W1F = (const f16x8*)ws + U_W1F;
    const f16x8* W2F = (const f16x8*)ws + U_W2F;
    const f16x8* W3F = (const f16x8*)ws + U_W3F;
    const f16x8* P0F = (const f16x8*)ws + U_P0F;
    const f16x8* B1F = (const f16x8*)ws + U_B1F;
    const f16x8* B2F = (const f16x8*)ws + U_B2F;

    __shared__ __align__(16) unsigned char lds[65536];

    const int tid  = threadIdx.x;
    const int w    = tid >> 6;       // wave 0..7
    const int lane = tid & 63;
    const int l31  = lane & 31;
    const int q    = lane >> 5;
    const size_t rowbase = (size_t)blockIdx.x * 64;

    f32x16 zero16;
#pragma unroll
    for (int i = 0; i < 16; ++i) zero16[i] = 0.f;

    // ones frag for bias-init MFMAs
    f16x8 ones;
#pragma unroll
    for (int e = 0; e < 8; ++e) ones[e] = (f16)0.f;
    if (q == 0) ones[0] = (f16)1.f;

    // X frags for both m-tiles (hi/lo split -> layer 1 ~exact)
    f16x8 xfrag[2];
#pragma unroll
    for (int mt = 0; mt < 2; ++mt) {
        f16x8 v;
#pragma unroll
        for (int e = 0; e < 8; ++e) v[e] = (f16)0.f;
        if (q == 0) {
            float2 xv = ((const float2*)X)[rowbase + mt * 32 + l31];
            f16 x0h = (f16)xv.x, x1h = (f16)xv.y;
            v[0] = x0h; v[1] = x1h; v[2] = (f16)1.f;
            v[3] = (f16)(xv.x - (float)x0h);
            v[4] = (f16)(xv.y - (float)x1h);
            v[5] = x0h; v[6] = x1h; v[7] = (f16)1.f;
        }
        xfrag[mt] = v;
    }

    // Layer-2 ownership: wave w -> j-tiles 2w, 2w+1; both m-tiles.
    const int jt0 = w * 2;
    f32x16 acc2[2][2];   // [ji][mt]
#pragma unroll
    for (int ji = 0; ji < 2; ++ji) {
        f32x16 binit = MFMA(B1F[(jt0 + ji) * 64 + lane], ones, zero16);
        acc2[ji][0] = binit;
        acc2[ji][1] = binit;
    }

    // ---- fused layer1 + layer2: K chunked 4 x 256 through slab (64 rows, rs=512B)
    for (int c = 0; c < 4; ++c) {
        // layer 1: wave w -> k1-tile w, both m-tiles
        {
            f16x8 af1 = P0F[(c * 8 + w) * 64 + lane];
            int kb = w * 32 + 4 * q;              // h1 feat (chunk-local)
#pragma unroll
            for (int mt = 0; mt < 2; ++mt) {
                f32x16 d = MFMA(af1, xfrag[mt], zero16);
                int m = mt * 32 + l31;            // batch row
#pragma unroll
                for (int t = 0; t < 4; ++t)
                    slab_write4(lds, m, (kb + 8 * t) >> 1, 512, relu_pack4(d, t));
            }
        }
        __syncthreads();
        // layer 2 partial K: 16 ks; 2 af (L2), 2 bf (LDS), 4 MFMA
#pragma unroll 4
        for (int ks = 0; ks < 16; ++ks) {
            int ksg = c * 16 + ks;
            f16x8 af0 = W1F[(jt0 * 64 + ksg) * 64 + lane];
            f16x8 af1 = W1F[((jt0 + 1) * 64 + ksg) * 64 + lane];
            int dw = (ks * 16 + q * 8) >> 1;
            f16x8 bf0 = slab_read8(lds, l31, dw, 512);
            f16x8 bf1 = slab_read8(lds, 32 + l31, dw, 512);
            acc2[0][0] = MFMA(af0, bf0, acc2[0][0]);
            acc2[0][1] = MFMA(af0, bf1, acc2[0][1]);
            acc2[1][0] = MFMA(af1, bf0, acc2[1][0]);
            acc2[1][1] = MFMA(af1, bf1, acc2[1][1]);
        }
        __syncthreads();
    }

    // ---- stage h2 (64 rows x 512 feats = 64KB, rs=1024B); acc2 dies here
#pragma unroll
    for (int ji = 0; ji < 2; ++ji) {
        int jb = (jt0 + ji) * 32 + 4 * q;
#pragma unroll
        for (int mt = 0; mt < 2; ++mt) {
            int m = mt * 32 + l31;
#pragma unroll
            for (int t = 0; t < 4; ++t)
                slab_write4(lds, m, (jb + 8 * t) >> 1, 1024,
                            relu_pack4(acc2[ji][mt], t));
        }
    }
    __syncthreads();

    // ---- layer 3 full-K (512): wave w -> j-tile w, both m-tiles
    f32x16 acc3[2];
    {
        f32x16 binit = MFMA(B2F[w * 64 + lane], ones, zero16);
        acc3[0] = binit;
        acc3[1] = binit;
    }
#pragma unroll 4
    for (int ks = 0; ks < 32; ++ks) {
        f16x8 af = W2F[(w * 32 + ks) * 64 + lane];
        int dw = (ks * 16 + q * 8) >> 1;
        f16x8 bf0 = slab_read8(lds, l31, dw, 1024);
        f16x8 bf1 = slab_read8(lds, 32 + l31, dw, 1024);
        acc3[0] = MFMA(af, bf0, acc3[0]);
        acc3[1] = MFMA(af, bf1, acc3[1]);
    }
    __syncthreads();   // h2 reads done before overwriting slab with h3

    // ---- stage h3 (64 rows x 256 feats = 32KB, rs=512B); acc3 dies here
    {
        int jb = w * 32 + 4 * q;
#pragma unroll
        for (int mt = 0; mt < 2; ++mt) {
            int m = mt * 32 + l31;
#pragma unroll
            for (int t = 0; t < 4; ++t)
                slab_write4(lds, m, (jb + 8 * t) >> 1, 512,
                            relu_pack4(acc3[mt], t));
        }
    }
    __syncthreads();

    // ---- layer 4: waves 0,1 -> the two 32-row tiles (j padded to 32, 3 valid)
    if (w < 2) {
        f32x16 acc4 = zero16;
#pragma unroll 4
        for (int ks = 0; ks < 16; ++ks) {
            f16x8 af = W3F[ks * 64 + lane];
            f16x8 bf = slab_read8(lds, w * 32 + l31, (ks * 16 + q * 8) >> 1, 512);
            acc4 = MFMA(af, bf, acc4);
        }
        if (q == 0) {
            size_t gm = rowbase + w * 32 + l31;
            out[gm * 3 + 0] = acc4[0] + b3[0];
            out[gm * 3 + 1] = acc4[1] + b3[1];
            out[gm * 3 + 2] = acc4[2] + b3[2];
        }
    }
}

extern "C" void kernel_launch(void* const* d_in, const int* in_sizes, int n_in,
                              void* d_out, int out_size, void* d_ws, size_t ws_size,
                              hipStream_t stream)
{
    const float* X  = (const float*)d_in[0];
    const float* W0 = (const float*)d_in[1];
    const float* b0 = (const float*)d_in[2];
    const float* W1 = (const float*)d_in[3];
    const float* b1 = (const float*)d_in[4];
    const float* W2 = (const float*)d_in[5];
    const float* b2 = (const float*)d_in[6];
    const float* W3 = (const float*)d_in[7];
    const float* b3 = (const float*)d_in[8];
    f16* ws = (f16*)d_ws;

    int N = in_sizes[0] / 2;          // 262144
    int nblk = N / 64;                // 4096

    prep_kernel<<<(U_TOTAL + 255) / 256, 256, 0, stream>>>(W0, b0, W1, b1, W2, b2, W3, ws);
    mlp_kernel<<<nblk, 512, 0, stream>>>(X, b3, ws, (float*)d_out);
}

// Round 7
// 408.628 us; speedup vs baseline: 2.3728x; 1.0343x over previous
//
#include <hip/hip_runtime.h>

// Fused 4-layer MLP (2 -> 1024 -> 512 -> 256 -> 3), N = 262144, fp32 I/O.
// R7: 512 threads (8 waves), 128 rows/block, 2048 blocks.
// Wave owns 2 jt x 4 mt -> acc2[2][4]=128 regs, 8 MFMAs per ks from 2 global
// + 4 LDS reads. __launch_bounds__(512,2) grants the 256-reg budget (R2-R5:
// never let the allocator target more waves than the acc footprint affords).
// fp16 MFMA 32x32x16, fp32 accumulate, transposed layers D[feat][batch].

typedef _Float16 f16;
typedef f16 f16x8 __attribute__((ext_vector_type(8)));
typedef f16 f16x4 __attribute__((ext_vector_type(4)));
typedef float f32x16 __attribute__((ext_vector_type(16)));

#define MFMA(a, b, c) __builtin_amdgcn_mfma_f32_32x32x16_f16((a), (b), (c), 0, 0, 0)

// ws layout in 16-byte units (f16x8):
//  W1F : [16 jt][64 ks][64 lane]            ->      0 .. 65536
//  W2F : [ 8 jt][32 ks][64 lane]            ->  65536 .. 81920
//  W3F : [16 ks][64 lane]                   ->  81920 .. 82944
//  P0F : [32 k1t][64 lane] (layer1 A frag)  ->  82944 .. 84992
//  B1F : [16 jt][64 lane]                   ->  84992 .. 86016
//  B2F : [ 8 jt][64 lane]                   ->  86016 .. 86528
#define U_W1F 0
#define U_W2F 65536
#define U_W3F 81920
#define U_P0F 82944
#define U_B1F 84992
#define U_B2F 86016
#define U_TOTAL 86528

__global__ void prep_kernel(const float* __restrict__ W0, const float* __restrict__ b0,
                            const float* __restrict__ W1, const float* __restrict__ b1,
                            const float* __restrict__ W2, const float* __restrict__ b2,
                            const float* __restrict__ W3, f16* __restrict__ ws)
{
    int u = blockIdx.x * 256 + threadIdx.x;
    if (u >= U_TOTAL) return;
    int lane = u & 63;
    int l31 = lane & 31;
    int q = lane >> 5;
    f16x8 v;
#pragma unroll
    for (int e = 0; e < 8; ++e) v[e] = (f16)0.f;

    if (u < U_W2F) {                       // W1F: W1 is [1024][512]
        int jt = u >> 12, ks = (u >> 6) & 63;
        int j = jt * 32 + l31;
        int kb = ks * 16 + q * 8;
        const float* p = W1 + (size_t)kb * 512 + j;
#pragma unroll
        for (int e = 0; e < 8; ++e) v[e] = (f16)p[(size_t)e * 512];
    } else if (u < U_W3F) {                // W2F: W2 is [512][256]
        int t = u - U_W2F;
        int jt = t >> 11, ks = (t >> 6) & 31;
        int j = jt * 32 + l31;
        int kb = ks * 16 + q * 8;
        const float* p = W2 + (size_t)kb * 256 + j;
#pragma unroll
        for (int e = 0; e < 8; ++e) v[e] = (f16)p[(size_t)e * 256];
    } else if (u < U_P0F) {                // W3F: W3 is [256][3], pad j>=3 with 0
        int t = u - U_W3F;
        int ks = t >> 6;
        int j = l31;
        int kb = ks * 16 + q * 8;
        if (j < 3) {
            const float* p = W3 + (size_t)kb * 3 + j;
#pragma unroll
            for (int e = 0; e < 8; ++e) v[e] = (f16)p[(size_t)e * 3];
        }
    } else if (u < U_B1F) {                // P0F: layer-1 A frag with hi/lo split + bias
        int t = u - U_P0F;
        int jt = t >> 6;
        int j = jt * 32 + l31;
        if (q == 0) {
            float w00 = W0[j], w01 = W0[1024 + j], bb = b0[j];
            f16 w00h = (f16)w00, w01h = (f16)w01, bh = (f16)bb;
            v[0] = w00h; v[1] = w01h; v[2] = bh;
            v[3] = w00h; v[4] = w01h;                       // pair with x_lo
            v[5] = (f16)(w00 - (float)w00h);                // w_lo * x_hi
            v[6] = (f16)(w01 - (float)w01h);
            v[7] = (f16)(bb - (float)bh);                   // bias residual * 1
        }
    } else if (u < U_B2F) {                // B1F
        int t = u - U_B1F;
        int jt = t >> 6;
        int j = jt * 32 + l31;
        if (q == 0) v[0] = (f16)b1[j];
    } else {                               // B2F
        int t = u - U_B2F;
        int jt = t >> 6;
        int j = jt * 32 + l31;
        if (q == 0) v[0] = (f16)b2[j];
    }
    ((f16x8*)ws)[u] = v;
}

// ---- LDS slab helpers. Slab rows: [m][k] f16, row stride rs bytes.
// XOR swizzle at 8-byte granularity: phys_dw = dw ^ ((m&15)<<1).
// 2-way-max bank conflicts (free) for both b64 writes and reads.
__device__ __forceinline__ void slab_write4(unsigned char* lds, int m, int dw /*even*/,
                                            int rs, f16x4 val)
{
    int s = (m & 15) << 1;
    *(f16x4*)(lds + (size_t)m * rs + (size_t)((dw ^ s) << 2)) = val;
}

__device__ __forceinline__ f16x8 slab_read8(const unsigned char* lds, int m, int dw /*mult of 4*/,
                                            int rs)
{
    int s = (m & 15) << 1;
    f16x4 lo = *(const f16x4*)(lds + (size_t)m * rs + (size_t)((dw ^ s) << 2));
    f16x4 hi = *(const f16x4*)(lds + (size_t)m * rs + (size_t)(((dw + 2) ^ s) << 2));
    union { f16x8 v; f16x4 p[2]; } u;
    u.p[0] = lo; u.p[1] = hi;
    return u.v;
}

__device__ __forceinline__ f16x4 relu_pack4(const f32x16& d, int t)
{
    f16x4 pk;
#pragma unroll
    for (int r = 0; r < 4; ++r) {
        float v = d[4 * t + r];
        pk[r] = (f16)(v > 0.f ? v : 0.f);
    }
    return pk;
}

__global__ __launch_bounds__(512, 2)
void mlp_kernel(const float* __restrict__ X, const float* __restrict__ b3,
                const f16* __restrict__ ws, float* __restrict__ out)
{
    const f16x8* W1F = (const f16x8*)ws + U_W1F;
    const f16x8* W2F = (const f16x8*)ws + U_W2F;
    const f16x8* W3F = (const f16x8*)ws + U_W3F;
    const f16x8* P0F = (const f16x8*)ws + U_P0F;
    const f16x8* B1F = (const f16x8*)ws + U_B1F;
    const f16x8* B2F = (const f16x8*)ws + U_B2F;

    __shared__ __align__(16) unsigned char lds[65536];

    const int tid  = threadIdx.x;
    const int w    = tid >> 6;       // wave 0..7
    const int lane = tid & 63;
    const int l31  = lane & 31;
    const int q    = lane >> 5;
    const size_t rowbase = (size_t)blockIdx.x * 128;

    f32x16 zero16;
#pragma unroll
    for (int i = 0; i < 16; ++i) zero16[i] = 0.f;

    // ones frag for bias-init MFMAs
    f16x8 ones;
#pragma unroll
    for (int e = 0; e < 8; ++e) ones[e] = (f16)0.f;
    if (q == 0) ones[0] = (f16)1.f;

    // X frags for all 4 m-tiles (hi/lo split -> layer 1 ~exact); 16 regs
    f16x8 xfrag[4];
#pragma unroll
    for (int mt = 0; mt < 4; ++mt) {
        f16x8 v;
#pragma unroll
        for (int e = 0; e < 8; ++e) v[e] = (f16)0.f;
        if (q == 0) {
            float2 xv = ((const float2*)X)[rowbase + mt * 32 + l31];
            f16 x0h = (f16)xv.x, x1h = (f16)xv.y;
            v[0] = x0h; v[1] = x1h; v[2] = (f16)1.f;
            v[3] = (f16)(xv.x - (float)x0h);
            v[4] = (f16)(xv.y - (float)x1h);
            v[5] = x0h; v[6] = x1h; v[7] = (f16)1.f;
        }
        xfrag[mt] = v;
    }

    // Layer-2 ownership: wave w -> j-tiles 2w, 2w+1; all 4 m-tiles.
    const int jt0 = w * 2;
    f32x16 acc2[2][4];   // [ji][mt] = 128 regs
#pragma unroll
    for (int ji = 0; ji < 2; ++ji) {
        f32x16 binit = MFMA(B1F[(jt0 + ji) * 64 + lane], ones, zero16);
#pragma unroll
        for (int mt = 0; mt < 4; ++mt) acc2[ji][mt] = binit;
    }

    // ---- fused layer1 + layer2: K chunked 4 x 256 through slab (128 rows, rs=512B)
    for (int c = 0; c < 4; ++c) {
        // layer 1: wave w -> k1-tile w (chunk-local), all 4 m-tiles
        {
            f16x8 af1 = P0F[(c * 8 + w) * 64 + lane];
            int kb = w * 32 + 4 * q;              // h1 feat (chunk-local)
#pragma unroll
            for (int mt = 0; mt < 4; ++mt) {
                f32x16 d = MFMA(af1, xfrag[mt], zero16);
                int m = mt * 32 + l31;            // batch row
#pragma unroll
                for (int t = 0; t < 4; ++t)
                    slab_write4(lds, m, (kb + 8 * t) >> 1, 512, relu_pack4(d, t));
            }
        }
        __syncthreads();
        // layer 2 partial K: 16 ks; 2 af (L2), 4 bf (LDS), 8 MFMA
#pragma unroll 4
        for (int ks = 0; ks < 16; ++ks) {
            int ksg = c * 16 + ks;
            f16x8 af0 = W1F[(jt0 * 64 + ksg) * 64 + lane];
            f16x8 af1 = W1F[((jt0 + 1) * 64 + ksg) * 64 + lane];
            int dw = (ks * 16 + q * 8) >> 1;
            f16x8 bf0 = slab_read8(lds, l31, dw, 512);
            f16x8 bf1 = slab_read8(lds, 32 + l31, dw, 512);
            f16x8 bf2 = slab_read8(lds, 64 + l31, dw, 512);
            f16x8 bf3 = slab_read8(lds, 96 + l31, dw, 512);
            acc2[0][0] = MFMA(af0, bf0, acc2[0][0]);
            acc2[0][1] = MFMA(af0, bf1, acc2[0][1]);
            acc2[0][2] = MFMA(af0, bf2, acc2[0][2]);
            acc2[0][3] = MFMA(af0, bf3, acc2[0][3]);
            acc2[1][0] = MFMA(af1, bf0, acc2[1][0]);
            acc2[1][1] = MFMA(af1, bf1, acc2[1][1]);
            acc2[1][2] = MFMA(af1, bf2, acc2[1][2]);
            acc2[1][3] = MFMA(af1, bf3, acc2[1][3]);
        }
        __syncthreads();
    }

    // ---- tail: two 64-row halves (h2 half = 64KB fits the slab)
#pragma unroll
    for (int mh = 0; mh < 2; ++mh) {
        // stage h2 half (64 rows x 512 feats, rs=1024B): wave w -> jt0, jt0+1
#pragma unroll
        for (int ji = 0; ji < 2; ++ji) {
            int jb = (jt0 + ji) * 32 + 4 * q;
#pragma unroll
            for (int u = 0; u < 2; ++u) {
                int m = u * 32 + l31;
#pragma unroll
                for (int t = 0; t < 4; ++t)
                    slab_write4(lds, m, (jb + 8 * t) >> 1, 1024,
                                relu_pack4(acc2[ji][mh * 2 + u], t));
            }
        }
        __syncthreads();
        // layer 3 (half): wave w -> j-tile w, both 32-row tiles; K=512
        f32x16 acc3[2];
        {
            f32x16 binit = MFMA(B2F[w * 64 + lane], ones, zero16);
            acc3[0] = binit;
            acc3[1] = binit;
        }
#pragma unroll 4
        for (int ks = 0; ks < 32; ++ks) {
            f16x8 af = W2F[(w * 32 + ks) * 64 + lane];
            int dw = (ks * 16 + q * 8) >> 1;
            f16x8 bf0 = slab_read8(lds, l31, dw, 1024);
            f16x8 bf1 = slab_read8(lds, 32 + l31, dw, 1024);
            acc3[0] = MFMA(af, bf0, acc3[0]);
            acc3[1] = MFMA(af, bf1, acc3[1]);
        }
        __syncthreads();
        // stage h3 half (64 rows x 256 feats, rs=512B)
        {
            int jb = w * 32 + 4 * q;
#pragma unroll
            for (int u = 0; u < 2; ++u) {
                int m = u * 32 + l31;
#pragma unroll
                for (int t = 0; t < 4; ++t)
                    slab_write4(lds, m, (jb + 8 * t) >> 1, 512,
                                relu_pack4(acc3[u], t));
            }
        }
        __syncthreads();
        // layer 4 (half): waves 0,1 -> the two 32-row tiles (j padded, 3 valid)
        if (w < 2) {
            f32x16 acc4 = zero16;
#pragma unroll 4
            for (int ks = 0; ks < 16; ++ks) {
                f16x8 af = W3F[ks * 64 + lane];
                f16x8 bf = slab_read8(lds, w * 32 + l31, (ks * 16 + q * 8) >> 1, 512);
                acc4 = MFMA(af, bf, acc4);
            }
            if (q == 0) {
                size_t gm = rowbase + mh * 64 + w * 32 + l31;
                out[gm * 3 + 0] = acc4[0] + b3[0];
                out[gm * 3 + 1] = acc4[1] + b3[1];
                out[gm * 3 + 2] = acc4[2] + b3[2];
            }
        }
        __syncthreads();   // slab reused by next half
    }
}

extern "C" void kernel_launch(void* const* d_in, const int* in_sizes, int n_in,
                              void* d_out, int out_size, void* d_ws, size_t ws_size,
                              hipStream_t stream)
{
    const float* X  = (const float*)d_in[0];
    const float* W0 = (const float*)d_in[1];
    const float* b0 = (const float*)d_in[2];
    const float* W1 = (const float*)d_in[3];
    const float* b1 = (const float*)d_in[4];
    const float* W2 = (const float*)d_in[5];
    const float* b2 = (const float*)d_in[6];
    const float* W3 = (const float*)d_in[7];
    const float* b3 = (const float*)d_in[8];
    f16* ws = (f16*)d_ws;

    int N = in_sizes[0] / 2;          // 262144
    int nblk = N / 128;               // 2048

    prep_kernel<<<(U_TOTAL + 255) / 256, 256, 0, stream>>>(W0, b0, W1, b1, W2, b2, W3, ws);
    mlp_kernel<<<nblk, 512, 0, stream>>>(X, b3, ws, (float*)d_out);
}